// Round 4
// baseline (242.224 us; speedup 1.0000x reference)
//
#include <hip/hip_runtime.h>
#include <cstdint>
#include <cstddef>

static constexpr int B_ = 2, S_ = 2048, D_ = 1024, H_ = 16, HD_ = 64;

typedef float f32x4 __attribute__((ext_vector_type(4)));
typedef short bf16x8 __attribute__((ext_vector_type(8)));

__device__ __forceinline__ unsigned short f2bf(float f) {
    union { float f; unsigned int u; } v; v.f = f;
    unsigned int r = v.u + 0x7FFFu + ((v.u >> 16) & 1u);   // RNE
    return (unsigned short)(r >> 16);
}

// 5-op RNE pair pack: bfe+add3 per value, one v_perm_b32 to gather the two
// high halves. Bit-identical to f2bf(a) | f2bf(b)<<16 (same adds, perm just
// selects bytes [ra.b2, ra.b3, rb.b2, rb.b3]). NO hardware cvt_pk (round-2
// failure: v_cvt_pk_bf16_f32 is not RNE-equivalent — do not reintroduce).
__device__ __forceinline__ unsigned pack2bf(float a, float b) {
    union { float f; unsigned u; } va, vb; va.f = a; vb.f = b;
    unsigned ra = va.u + 0x7FFFu + ((va.u >> 16) & 1u);
    unsigned rb = vb.u + 0x7FFFu + ((vb.u >> 16) & 1u);
    return __builtin_amdgcn_perm(rb, ra, 0x07060302u);
}

// async global->LDS, 16B per lane. LDS dest = wave-uniform base + lane*16.
__device__ __forceinline__ void gload_lds16(const void* g, void* l) {
    __builtin_amdgcn_global_load_lds(
        (const __attribute__((address_space(1))) void*)g,
        (__attribute__((address_space(3))) void*)l, 16, 0, 0);
}

// ---------------------------------------------------------------------------
// Fused prep: [0,2048) cast x->bf16 | [2048,4096) mask int32->u8 (0xFF/0x00) |
// [4096,4864) W transpose+cast.
// ---------------------------------------------------------------------------
__global__ __launch_bounds__(256)
void prep(const float* __restrict__ x, unsigned short* __restrict__ xo,
          const int* __restrict__ m, unsigned char* __restrict__ mo,
          const float* __restrict__ Wq, const float* __restrict__ Wk,
          const float* __restrict__ Wv, unsigned short* __restrict__ wt) {
    __shared__ unsigned short Ts[64][72];
    const int bid = blockIdx.x, t = threadIdx.x;
    if (bid < 2048) {
        size_t i = ((size_t)bid * 256 + t) * 8;
        float4 a = *(const float4*)(x + i);
        float4 c = *(const float4*)(x + i + 4);
        uint4 r;
        r.x = pack2bf(a.x, a.y); r.y = pack2bf(a.z, a.w);
        r.z = pack2bf(c.x, c.y); r.w = pack2bf(c.z, c.w);
        *(uint4*)(xo + i) = r;
    } else if (bid < 4096) {
        size_t i = ((size_t)(bid - 2048) * 256 + t) * 16;
        uint4 r;
        unsigned w[4];
        #pragma unroll
        for (int g = 0; g < 4; ++g) {
            int4 v = *(const int4*)(m + i + g * 4);
            w[g] = (v.x ? 0xFFu : 0u) | (v.y ? 0xFF00u : 0u) |
                   (v.z ? 0xFF0000u : 0u) | (v.w ? 0xFF000000u : 0u);
        }
        r.x = w[0]; r.y = w[1]; r.z = w[2]; r.w = w[3];
        *(uint4*)(mo + i) = r;
    } else {
        const int tid = bid - 4096;            // 0..767
        const int mat = tid >> 8, tile = tid & 255;
        const float* __restrict__ W = (mat == 0) ? Wq : (mat == 1) ? Wk : Wv;
        unsigned short* __restrict__ o = wt + (size_t)mat * D_ * D_;
        const int n0 = (tile & 15) * 64, k0 = (tile >> 4) * 64;
        {
            const int nl = t & 63, kb = t >> 6;
            #pragma unroll
            for (int i = 0; i < 16; ++i) {
                int k = kb + i * 4;
                Ts[nl][k] = f2bf(W[(size_t)(k0 + k) * D_ + n0 + nl]);
            }
        }
        __syncthreads();
        {
            const int kl = t & 63, nb = t >> 6;
            #pragma unroll
            for (int i = 0; i < 16; ++i) {
                int n = nb + i * 4;
                o[(size_t)(n0 + n) * D_ + k0 + kl] = Ts[n][kl];
            }
        }
    }
}

// ---------------------------------------------------------------------------
// QKV GEMM, bf16 MFMA 16x16x32. 128x128 tile, BK=32. (unchanged, passing)
// ---------------------------------------------------------------------------
__global__ __launch_bounds__(256)
void qkv_gemm(const unsigned short* __restrict__ xb, const unsigned short* __restrict__ wt,
              const float* __restrict__ bq, const float* __restrict__ bk,
              const float* __restrict__ bv,
              unsigned short* __restrict__ qo, unsigned short* __restrict__ ko,
              unsigned short* __restrict__ vto) {
    const int bx = blockIdx.x;            // 0..23: mat*8 + ntile
    const int by = blockIdx.y;            // 0..31: mtile
    const int mat = bx >> 3;
    const int ncol0 = (bx & 7) * 128;
    const float* __restrict__ bias = (mat == 0) ? bq : (mat == 1) ? bk : bv;
    const unsigned short* __restrict__ Wm = wt + (size_t)mat * D_ * D_;

    __shared__ unsigned short As[2][128 * 32];
    __shared__ unsigned short Bs[2][128 * 32];

    const int t = threadIdx.x;
    const int w = t >> 6, lane = t & 63;
    const int l15 = lane & 15, quad = lane >> 4;
    const int mw = (w >> 1) * 64, nw = (w & 1) * 64;
    const int rowBase = by * 128;

    const int r16 = lane >> 2;                       // 0..15
    const int sslot = lane & 3;
    const int sg = (sslot ^ ((r16 >> 1) & 3)) * 8;   // staged global col (shorts)
    const int rcol = (quad ^ ((l15 >> 1) & 3)) * 8;  // fragment read col (shorts)

    f32x4 acc[4][4] = {};

    #pragma unroll
    for (int j = 0; j < 2; ++j) {
        const int r0 = w * 32 + j * 16;
        gload_lds16(xb + (size_t)(rowBase + r0 + r16) * D_ + sg, &As[0][r0 * 32]);
        gload_lds16(Wm + (size_t)(ncol0 + r0 + r16) * D_ + sg, &Bs[0][r0 * 32]);
    }

    for (int it = 0; it < 32; ++it) {
        const int cur = it & 1;
        __syncthreads();
        if (it + 1 < 32) {
            const int ktn = (it + 1) * 32;
            #pragma unroll
            for (int j = 0; j < 2; ++j) {
                const int r0 = w * 32 + j * 16;
                gload_lds16(xb + (size_t)(rowBase + r0 + r16) * D_ + ktn + sg,
                            &As[cur ^ 1][r0 * 32]);
                gload_lds16(Wm + (size_t)(ncol0 + r0 + r16) * D_ + ktn + sg,
                            &Bs[cur ^ 1][r0 * 32]);
            }
        }

        bf16x8 a[4], b[4];
        #pragma unroll
        for (int i = 0; i < 4; ++i)
            a[i] = *(const bf16x8*)&As[cur][(mw + i * 16 + l15) * 32 + rcol];
        #pragma unroll
        for (int j = 0; j < 4; ++j)
            b[j] = *(const bf16x8*)&Bs[cur][(nw + j * 16 + l15) * 32 + rcol];
        #pragma unroll
        for (int i = 0; i < 4; ++i)
            #pragma unroll
            for (int j = 0; j < 4; ++j)
                acc[i][j] = __builtin_amdgcn_mfma_f32_16x16x32_bf16(a[i], b[j], acc[i][j], 0, 0, 0);
    }

    if (mat < 2) {
        unsigned short* __restrict__ O = (mat == 0) ? qo : ko;
        const float osc = (mat == 0) ? 0.18033688011112443f : 1.0f;  // 0.125*log2(e)
        #pragma unroll
        for (int j = 0; j < 4; ++j) {
            const int col = ncol0 + nw + j * 16 + l15;
            const float bb = bias[col];
            #pragma unroll
            for (int i = 0; i < 4; ++i)
                #pragma unroll
                for (int r = 0; r < 4; ++r) {
                    const int m = rowBase + mw + i * 16 + quad * 4 + r;
                    O[(size_t)m * D_ + col] = f2bf((acc[i][j][r] + bb) * osc);
                }
        }
    } else {
        #pragma unroll
        for (int j = 0; j < 4; ++j) {
            const int col = ncol0 + nw + j * 16 + l15;
            const float bb = bias[col];
            const int hh = col >> 6, hd = col & 63;
            #pragma unroll
            for (int i = 0; i < 4; ++i) {
                const int m0 = rowBase + mw + i * 16 + quad * 4;
                const int bg = m0 >> 11, s0 = m0 & 2047;
                ushort4 pk;
                pk.x = f2bf(acc[i][j][0] + bb);
                pk.y = f2bf(acc[i][j][1] + bb);
                pk.z = f2bf(acc[i][j][2] + bb);
                pk.w = f2bf(acc[i][j][3] + bb);
                *(ushort4*)&vto[(((size_t)bg * H_ + hh) * HD_ + hd) * S_ + s0] = pk;
            }
        }
    }
}

// ---------------------------------------------------------------------------
// Flash attention, bf16 MFMA, S^T orientation, Q in registers. 8 waves,
// QT=128 rows/block, 512-block grid (2 blocks/CU, 16 waves/CU).
// KVBLK=128: stage 128 keys per outer iter as 2x64-key panels; two inner
// sub-steps share ONE barrier -> 16 barrier/vmcnt drains instead of 32,
// and prefetch DMA gets ~2 sub-steps of compute to land under.
// LDS 80KB (Ks 32 + Vs 32 + Ps 16) -> still 2 blocks/CU (grid is the cap).
// Swizzle invariants unchanged: staged row&7 = rs, read row&7 = l15&7.
// Mask select: 0xFF bytes -> v_perm byte-replicate -> bfi merge (masked ->
// exact bf16 1.0, reference quirk). Q pre-scaled by 0.125*log2e.
// Numerics bit-identical to round 3 (software RNE everywhere).
// ---------------------------------------------------------------------------
__global__ __launch_bounds__(512, 4)
void attn_mfma(const unsigned short* __restrict__ qmat,
               const unsigned short* __restrict__ kmat,
               const unsigned short* __restrict__ vtg,
               const unsigned char* __restrict__ msk, float* __restrict__ out) {
    const int h = blockIdx.x, qt = blockIdx.y, b = blockIdx.z;
    const int t = threadIdx.x, w = t >> 6, lane = t & 63;
    const int l15 = lane & 15, quad = lane >> 4;
    const int q0 = qt * 128;

    __shared__ unsigned short Ks[2][2][64 * 64];           // [buf][panel][key][d]
    __shared__ unsigned short Vs[2][2][64 * 64];           // [buf][panel][d][key]
    __shared__ __align__(16) unsigned short Ps[128 * 64];  // [qrow][key] swizzled

    const size_t bh = (size_t)b * S_ * D_ + (size_t)h * HD_;
    const unsigned short* __restrict__ qp = qmat + bh;
    const unsigned short* __restrict__ kp = kmat + bh;
    const unsigned short* __restrict__ vp = vtg + ((size_t)b * H_ + h) * HD_ * S_;
    const unsigned char* __restrict__ mb = msk + (size_t)b * S_ * S_;

    const int rs = lane >> 3, sslot = lane & 7;
    const int sg = (sslot ^ rs) * 8;         // staged global granule col (shorts)
    const int srow = w * 8 + rs;             // staging row 0..63 (8 rows/wave)

    const int qr = w * 16 + l15;             // this thread's q-row strip index
    const int sw7 = l15 & 7;                 // = qr & 7 (row swizzle key)

    // Q fragments in registers (loop-invariant)
    bf16x8 qfr[2];
    #pragma unroll
    for (int kst = 0; kst < 2; ++kst)
        qfr[kst] = *(const bf16x8*)(qp + (size_t)(q0 + qr) * D_ + kst * 32 + quad * 8);

    f32x4 accO[4] = {};
    f32x4 lsA = {};
    bf16x8 ones;
    #pragma unroll
    for (int i = 0; i < 8; ++i) ones[i] = (short)0x3F80;   // bf16 1.0

    // prologue: stage keys 0..127 into buffer 0 (both panels)
    #pragma unroll
    for (int half = 0; half < 2; ++half) {
        gload_lds16(kp + (size_t)(half * 64 + srow) * D_ + sg, &Ks[0][half][w * 8 * 64]);
        gload_lds16(vp + (size_t)srow * S_ + half * 64 + sg, &Vs[0][half][w * 8 * 64]);
    }

    for (int it = 0; it < 16; ++it) {
        const int cur = it & 1;
        const int kt = it * 128;
        __syncthreads();   // buf cur DMA drained; readers of buf cur^1 done

        // 1) mask loads first (vmcnt FIFO: waiting on these won't drain DMA)
        unsigned mu[2][4];
        {
            const unsigned char* __restrict__ mrow = mb + (size_t)(q0 + qr) * S_ + kt;
            #pragma unroll
            for (int ks2 = 0; ks2 < 2; ++ks2)
                #pragma unroll
                for (int mt = 0; mt < 4; ++mt)
                    mu[ks2][mt] = *(const unsigned*)(mrow + ks2 * 64 + mt * 16 + quad * 4);
        }

        // 2) prefetch next 128-key tile into the other buffer
        if (it + 1 < 16) {
            const int ktn = kt + 128;
            #pragma unroll
            for (int half = 0; half < 2; ++half) {
                gload_lds16(kp + (size_t)(ktn + half * 64 + srow) * D_ + sg,
                            &Ks[cur ^ 1][half][w * 8 * 64]);
                gload_lds16(vp + (size_t)srow * S_ + ktn + half * 64 + sg,
                            &Vs[cur ^ 1][half][w * 8 * 64]);
            }
        }

        // two 64-key sub-steps, no barrier between (Ps is wave-private)
        #pragma unroll
        for (int ks2 = 0; ks2 < 2; ++ks2) {
            const unsigned short* __restrict__ Kp_ = &Ks[cur][ks2][0];
            const unsigned short* __restrict__ Vp_ = &Vs[cur][ks2][0];

            // 3) S^T = K·Q^T : m = 64 keys (4 tiles), n = wave's 16 qrows
            f32x4 sc[4] = {};
            #pragma unroll
            for (int kst = 0; kst < 2; ++kst) {
                bf16x8 kfr[4];
                #pragma unroll
                for (int mt = 0; mt < 4; ++mt) {
                    const int R = mt * 16 + l15;
                    kfr[mt] = *(const bf16x8*)&Kp_[R * 64 + (((kst * 4 + quad) ^ sw7) * 8)];
                }
                __builtin_amdgcn_s_setprio(1);
                #pragma unroll
                for (int mt = 0; mt < 4; ++mt)
                    sc[mt] = __builtin_amdgcn_mfma_f32_16x16x32_bf16(kfr[mt], qfr[kst], sc[mt], 0, 0, 0);
                __builtin_amdgcn_s_setprio(0);
            }

            // 4) exp2 + 5-op pack + perm/bfi mask-merge + swizzled P^T store
            #pragma unroll
            for (int mt = 0; mt < 4; ++mt) {
                unsigned p0 = pack2bf(__builtin_amdgcn_exp2f(sc[mt][0]),
                                      __builtin_amdgcn_exp2f(sc[mt][1]));
                unsigned p1 = pack2bf(__builtin_amdgcn_exp2f(sc[mt][2]),
                                      __builtin_amdgcn_exp2f(sc[mt][3]));
                const unsigned m0 = __builtin_amdgcn_perm(0u, mu[ks2][mt], 0x01010000u);
                const unsigned m1 = __builtin_amdgcn_perm(0u, mu[ks2][mt], 0x03030202u);
                p0 = (m0 & 0x3F803F80u) | (~m0 & p0);   // v_bfi: masked -> bf16 1.0
                p1 = (m1 & 0x3F803F80u) | (~m1 & p1);
                uint2 pk2; pk2.x = p0; pk2.y = p1;
                *(uint2*)((char*)Ps + qr * 128 +
                          (((2 * mt + (quad >> 1)) ^ sw7) * 16) + (quad & 1) * 8) = pk2;
            }

            // 5) O += P·V ; lsum += P·1
            #pragma unroll
            for (int kst = 0; kst < 2; ++kst) {
                bf16x8 vfr[4];
                #pragma unroll
                for (int dt = 0; dt < 4; ++dt) {
                    const int R = dt * 16 + l15;
                    vfr[dt] = *(const bf16x8*)&Vp_[R * 64 + (((kst * 4 + quad) ^ sw7) * 8)];
                }
                bf16x8 pfr = *(const bf16x8*)((const char*)Ps + qr * 128 +
                                              (((kst * 4 + quad) ^ sw7) * 16));
                __builtin_amdgcn_s_setprio(1);
                #pragma unroll
                for (int dt = 0; dt < 4; ++dt)
                    accO[dt] = __builtin_amdgcn_mfma_f32_16x16x32_bf16(pfr, vfr[dt], accO[dt], 0, 0, 0);
                lsA = __builtin_amdgcn_mfma_f32_16x16x32_bf16(pfr, ones, lsA, 0, 0, 0);
                __builtin_amdgcn_s_setprio(0);
            }
        }
    }

    // normalize + store
    float* __restrict__ ob = out + ((size_t)b * S_ + q0) * D_ + (size_t)h * HD_;
    #pragma unroll
    for (int r = 0; r < 4; ++r) {
        const float inv = 1.0f / lsA[r];
        const int row = w * 16 + quad * 4 + r;
        #pragma unroll
        for (int dt = 0; dt < 4; ++dt)
            ob[(size_t)row * D_ + dt * 16 + l15] = accO[dt][r] * inv;
    }
}

extern "C" void kernel_launch(void* const* d_in, const int* in_sizes, int n_in,
                              void* d_out, int out_size, void* d_ws, size_t ws_size,
                              hipStream_t stream) {
    (void)in_sizes; (void)n_in; (void)out_size; (void)ws_size;
    const float* x    = (const float*)d_in[0];
    const int*   mask = (const int*)d_in[1];
    const float* Wq   = (const float*)d_in[2];
    const float* bq   = (const float*)d_in[3];
    const float* Wk   = (const float*)d_in[4];
    const float* bk   = (const float*)d_in[5];
    const float* Wv   = (const float*)d_in[6];
    const float* bv   = (const float*)d_in[7];
    float* out = (float*)d_out;

    const size_t M1 = (size_t)1024 * 1024;
    unsigned short* xb  = (unsigned short*)d_ws;      // 4M bf16
    unsigned short* wtb = xb + 4 * M1;                // 3M bf16
    unsigned short* qb  = wtb + 3 * M1;               // 4M bf16
    unsigned short* kb  = qb + 4 * M1;                // 4M bf16
    unsigned short* vtb = kb + 4 * M1;                // 4M bf16 (transposed V)
    unsigned char*  mk  = (unsigned char*)(vtb + 4 * M1);  // 8M u8 (0xFF/0x00)

    prep<<<4864, 256, 0, stream>>>(x, xb, mask, mk, Wq, Wk, Wv, wtb);
    qkv_gemm<<<dim3(24, 32), 256, 0, stream>>>(xb, wtb, bq, bk, bv, qb, kb, vtb);
    attn_mfma<<<dim3(16, 16, 2), 512, 0, stream>>>(qb, kb, vtb, mk, out);
}

// Round 5
// 208.431 us; speedup vs baseline: 1.1621x; 1.1621x over previous
//
#include <hip/hip_runtime.h>
#include <cstdint>
#include <cstddef>

static constexpr int B_ = 2, S_ = 2048, D_ = 1024, H_ = 16, HD_ = 64;

typedef float f32x4 __attribute__((ext_vector_type(4)));
typedef short bf16x8 __attribute__((ext_vector_type(8)));

__device__ __forceinline__ unsigned short f2bf(float f) {
    union { float f; unsigned int u; } v; v.f = f;
    unsigned int r = v.u + 0x7FFFu + ((v.u >> 16) & 1u);   // RNE
    return (unsigned short)(r >> 16);
}

// 5-op RNE pair pack: add per value, one v_perm_b32 to gather the two high
// halves. Bit-identical to f2bf(a) | f2bf(b)<<16. NO hardware cvt_pk
// (round-2 failure: v_cvt_pk_bf16_f32 is not RNE-equivalent).
__device__ __forceinline__ unsigned pack2bf(float a, float b) {
    union { float f; unsigned u; } va, vb; va.f = a; vb.f = b;
    unsigned ra = va.u + 0x7FFFu + ((va.u >> 16) & 1u);
    unsigned rb = vb.u + 0x7FFFu + ((vb.u >> 16) & 1u);
    return __builtin_amdgcn_perm(rb, ra, 0x07060302u);
}

// async global->LDS, 16B per lane. LDS dest = wave-uniform base + lane*16.
__device__ __forceinline__ void gload_lds16(const void* g, void* l) {
    __builtin_amdgcn_global_load_lds(
        (const __attribute__((address_space(1))) void*)g,
        (__attribute__((address_space(3))) void*)l, 16, 0, 0);
}

// ---------------------------------------------------------------------------
// Fused prep: [0,2048) cast x->bf16 | [2048,4096) mask int32->u8 (0xFF/0x00) |
// [4096,4864) W transpose+cast.
// ---------------------------------------------------------------------------
__global__ __launch_bounds__(256)
void prep(const float* __restrict__ x, unsigned short* __restrict__ xo,
          const int* __restrict__ m, unsigned char* __restrict__ mo,
          const float* __restrict__ Wq, const float* __restrict__ Wk,
          const float* __restrict__ Wv, unsigned short* __restrict__ wt) {
    __shared__ unsigned short Ts[64][72];
    const int bid = blockIdx.x, t = threadIdx.x;
    if (bid < 2048) {
        size_t i = ((size_t)bid * 256 + t) * 8;
        float4 a = *(const float4*)(x + i);
        float4 c = *(const float4*)(x + i + 4);
        uint4 r;
        r.x = pack2bf(a.x, a.y); r.y = pack2bf(a.z, a.w);
        r.z = pack2bf(c.x, c.y); r.w = pack2bf(c.z, c.w);
        *(uint4*)(xo + i) = r;
    } else if (bid < 4096) {
        size_t i = ((size_t)(bid - 2048) * 256 + t) * 16;
        uint4 r;
        unsigned w[4];
        #pragma unroll
        for (int g = 0; g < 4; ++g) {
            int4 v = *(const int4*)(m + i + g * 4);
            w[g] = (v.x ? 0xFFu : 0u) | (v.y ? 0xFF00u : 0u) |
                   (v.z ? 0xFF0000u : 0u) | (v.w ? 0xFF000000u : 0u);
        }
        r.x = w[0]; r.y = w[1]; r.z = w[2]; r.w = w[3];
        *(uint4*)(mo + i) = r;
    } else {
        const int tid = bid - 4096;            // 0..767
        const int mat = tid >> 8, tile = tid & 255;
        const float* __restrict__ W = (mat == 0) ? Wq : (mat == 1) ? Wk : Wv;
        unsigned short* __restrict__ o = wt + (size_t)mat * D_ * D_;
        const int n0 = (tile & 15) * 64, k0 = (tile >> 4) * 64;
        {
            const int nl = t & 63, kb = t >> 6;
            #pragma unroll
            for (int i = 0; i < 16; ++i) {
                int k = kb + i * 4;
                Ts[nl][k] = f2bf(W[(size_t)(k0 + k) * D_ + n0 + nl]);
            }
        }
        __syncthreads();
        {
            const int kl = t & 63, nb = t >> 6;
            #pragma unroll
            for (int i = 0; i < 16; ++i) {
                int n = nb + i * 4;
                o[(size_t)(n0 + n) * D_ + k0 + kl] = Ts[n][kl];
            }
        }
    }
}

// ---------------------------------------------------------------------------
// QKV GEMM, bf16 MFMA 16x16x32. 128x128 tile, BK=32, double-buffered DMA.
// NOW 512 threads (8 waves, wave-tile 64x32): same grid (768 blocks), same
// LDS (32KB), same staging bytes, but 24 waves/CU (6/SIMD) vs 12 — the
// round-3 occupancy lever applied to qkv. Staging: 1 gload/thread/matrix.
// Swizzle invariants: staged key (srow>>1)&3 = (r16>>1)&3; read key
// (R>>1)&3 = (l15>>1)&3 (wave offsets vanish mod 4 after >>1).
// Accumulation order per output element unchanged -> bit-identical.
// ---------------------------------------------------------------------------
__global__ __launch_bounds__(512)
void qkv_gemm(const unsigned short* __restrict__ xb, const unsigned short* __restrict__ wt,
              const float* __restrict__ bq, const float* __restrict__ bk,
              const float* __restrict__ bv,
              unsigned short* __restrict__ qo, unsigned short* __restrict__ ko,
              unsigned short* __restrict__ vto) {
    const int bx = blockIdx.x;            // 0..23: mat*8 + ntile
    const int by = blockIdx.y;            // 0..31: mtile
    const int mat = bx >> 3;
    const int ncol0 = (bx & 7) * 128;
    const float* __restrict__ bias = (mat == 0) ? bq : (mat == 1) ? bk : bv;
    const unsigned short* __restrict__ Wm = wt + (size_t)mat * D_ * D_;

    __shared__ unsigned short As[2][128 * 32];
    __shared__ unsigned short Bs[2][128 * 32];

    const int t = threadIdx.x;
    const int w = t >> 6, lane = t & 63;
    const int l15 = lane & 15, quad = lane >> 4;
    const int mw = (w >> 2) * 64, nw = (w & 3) * 32;   // wave tile 64x32
    const int rowBase = by * 128;

    const int r16 = lane >> 2;                       // 0..15
    const int sslot = lane & 3;
    const int sg = (sslot ^ ((r16 >> 1) & 3)) * 8;   // staged global col (shorts)
    const int srow = w * 16 + r16;                   // staging row 0..127
    const int rcol = (quad ^ ((l15 >> 1) & 3)) * 8;  // fragment read col (shorts)

    f32x4 acc[4][2] = {};

    // prologue: stage kt=0 into buffer 0 (1 load/thread per matrix)
    gload_lds16(xb + (size_t)(rowBase + srow) * D_ + sg, &As[0][w * 16 * 32]);
    gload_lds16(Wm + (size_t)(ncol0 + srow) * D_ + sg, &Bs[0][w * 16 * 32]);

    for (int it = 0; it < 32; ++it) {
        const int cur = it & 1;
        __syncthreads();   // drains own DMA (buf cur ready); readers of cur^1 done
        if (it + 1 < 32) {
            const int ktn = (it + 1) * 32;
            gload_lds16(xb + (size_t)(rowBase + srow) * D_ + ktn + sg,
                        &As[cur ^ 1][w * 16 * 32]);
            gload_lds16(Wm + (size_t)(ncol0 + srow) * D_ + ktn + sg,
                        &Bs[cur ^ 1][w * 16 * 32]);
        }

        bf16x8 a[4], b[2];
        #pragma unroll
        for (int i = 0; i < 4; ++i)
            a[i] = *(const bf16x8*)&As[cur][(mw + i * 16 + l15) * 32 + rcol];
        #pragma unroll
        for (int j = 0; j < 2; ++j)
            b[j] = *(const bf16x8*)&Bs[cur][(nw + j * 16 + l15) * 32 + rcol];
        #pragma unroll
        for (int i = 0; i < 4; ++i)
            #pragma unroll
            for (int j = 0; j < 2; ++j)
                acc[i][j] = __builtin_amdgcn_mfma_f32_16x16x32_bf16(a[i], b[j], acc[i][j], 0, 0, 0);
    }

    if (mat < 2) {
        unsigned short* __restrict__ O = (mat == 0) ? qo : ko;
        const float osc = (mat == 0) ? 0.18033688011112443f : 1.0f;  // 0.125*log2(e)
        #pragma unroll
        for (int j = 0; j < 2; ++j) {
            const int col = ncol0 + nw + j * 16 + l15;
            const float bb = bias[col];
            #pragma unroll
            for (int i = 0; i < 4; ++i)
                #pragma unroll
                for (int r = 0; r < 4; ++r) {
                    const int m = rowBase + mw + i * 16 + quad * 4 + r;
                    O[(size_t)m * D_ + col] = f2bf((acc[i][j][r] + bb) * osc);
                }
        }
    } else {
        #pragma unroll
        for (int j = 0; j < 2; ++j) {
            const int col = ncol0 + nw + j * 16 + l15;
            const float bb = bias[col];
            const int hh = col >> 6, hd = col & 63;
            #pragma unroll
            for (int i = 0; i < 4; ++i) {
                const int m0 = rowBase + mw + i * 16 + quad * 4;
                const int bg = m0 >> 11, s0 = m0 & 2047;
                ushort4 pk;
                pk.x = f2bf(acc[i][j][0] + bb);
                pk.y = f2bf(acc[i][j][1] + bb);
                pk.z = f2bf(acc[i][j][2] + bb);
                pk.w = f2bf(acc[i][j][3] + bb);
                *(ushort4*)&vto[(((size_t)bg * H_ + hh) * HD_ + hd) * S_ + s0] = pk;
            }
        }
    }
}

// ---------------------------------------------------------------------------
// Flash attention — EXACT round-3 structure (82us, best measured).
// 8 waves, QT=128 rows/block, 512-block grid, KVBLK=64, LDS 48KB.
// (Round-4 KVBLK=128 regressed: +32KB LDS pinned occupancy, bigger per-iter
// code; barrier count was not the binding constraint.)
// ---------------------------------------------------------------------------
__global__ __launch_bounds__(512, 4)
void attn_mfma(const unsigned short* __restrict__ qmat,
               const unsigned short* __restrict__ kmat,
               const unsigned short* __restrict__ vtg,
               const unsigned char* __restrict__ msk, float* __restrict__ out) {
    const int h = blockIdx.x, qt = blockIdx.y, b = blockIdx.z;
    const int t = threadIdx.x, w = t >> 6, lane = t & 63;
    const int l15 = lane & 15, quad = lane >> 4;
    const int q0 = qt * 128;

    __shared__ unsigned short Ks[2][64 * 64];              // [key][d] swizzled
    __shared__ unsigned short Vs[2][64 * 64];              // [d][key] swizzled
    __shared__ __align__(16) unsigned short Ps[128 * 64];  // [qrow][key] swizzled

    const size_t bh = (size_t)b * S_ * D_ + (size_t)h * HD_;
    const unsigned short* __restrict__ qp = qmat + bh;
    const unsigned short* __restrict__ kp = kmat + bh;
    const unsigned short* __restrict__ vp = vtg + ((size_t)b * H_ + h) * HD_ * S_;
    const unsigned char* __restrict__ mb = msk + (size_t)b * S_ * S_;

    const int rs = lane >> 3, sslot = lane & 7;
    const int sg = (sslot ^ rs) * 8;         // staged global granule col (shorts)
    const int srow = w * 8 + rs;             // staging row 0..63 (8 rows/wave)

    const int qr = w * 16 + l15;             // this thread's q-row strip index
    const int sw7 = l15 & 7;                 // = qr & 7 (row swizzle key)

    // Q fragments in registers (loop-invariant)
    bf16x8 qfr[2];
    #pragma unroll
    for (int kst = 0; kst < 2; ++kst)
        qfr[kst] = *(const bf16x8*)(qp + (size_t)(q0 + qr) * D_ + kst * 32 + quad * 8);

    f32x4 accO[4] = {};
    f32x4 lsA = {};
    bf16x8 ones;
    #pragma unroll
    for (int i = 0; i < 8; ++i) ones[i] = (short)0x3F80;   // bf16 1.0

    // prologue: stage tile 0 into buffer 0 (one 16B DMA per thread per matrix)
    gload_lds16(kp + (size_t)srow * D_ + sg, &Ks[0][w * 8 * 64]);
    gload_lds16(vp + (size_t)srow * S_ + sg, &Vs[0][w * 8 * 64]);

    for (int it = 0; it < 32; ++it) {
        const int cur = it & 1;
        const int kt = it * 64;
        __syncthreads();   // buf cur DMA drained; readers of buf cur^1 done

        // 1) mask loads first (vmcnt FIFO: waiting on these won't drain DMA)
        unsigned mu[4];
        {
            const unsigned char* __restrict__ mrow = mb + (size_t)(q0 + qr) * S_ + kt;
            #pragma unroll
            for (int mt = 0; mt < 4; ++mt)
                mu[mt] = *(const unsigned*)(mrow + mt * 16 + quad * 4);
        }

        // 2) prefetch next tile into the other buffer
        if (it + 1 < 32) {
            const int ktn = kt + 64;
            gload_lds16(kp + (size_t)(ktn + srow) * D_ + sg, &Ks[cur ^ 1][w * 8 * 64]);
            gload_lds16(vp + (size_t)srow * S_ + ktn + sg, &Vs[cur ^ 1][w * 8 * 64]);
        }

        // 3) S^T = K·Q^T : m = 64 keys (4 tiles), n = wave's 16 qrows
        f32x4 sc[4] = {};
        #pragma unroll
        for (int kst = 0; kst < 2; ++kst) {
            bf16x8 kfr[4];
            #pragma unroll
            for (int mt = 0; mt < 4; ++mt) {
                const int R = mt * 16 + l15;
                kfr[mt] = *(const bf16x8*)&Ks[cur][R * 64 + (((kst * 4 + quad) ^ sw7) * 8)];
            }
            __builtin_amdgcn_s_setprio(1);
            #pragma unroll
            for (int mt = 0; mt < 4; ++mt)
                sc[mt] = __builtin_amdgcn_mfma_f32_16x16x32_bf16(kfr[mt], qfr[kst], sc[mt], 0, 0, 0);
            __builtin_amdgcn_s_setprio(0);
        }

        // 4) exp2 + pack + perm/bfi mask-merge + swizzled P^T store (wave-private)
        #pragma unroll
        for (int mt = 0; mt < 4; ++mt) {
            unsigned p0 = pack2bf(__builtin_amdgcn_exp2f(sc[mt][0]),
                                  __builtin_amdgcn_exp2f(sc[mt][1]));
            unsigned p1 = pack2bf(__builtin_amdgcn_exp2f(sc[mt][2]),
                                  __builtin_amdgcn_exp2f(sc[mt][3]));
            const unsigned m0 = __builtin_amdgcn_perm(0u, mu[mt], 0x01010000u); // [b0,b0,b1,b1]
            const unsigned m1 = __builtin_amdgcn_perm(0u, mu[mt], 0x03030202u); // [b2,b2,b3,b3]
            p0 = (m0 & 0x3F803F80u) | (~m0 & p0);   // v_bfi: masked -> bf16 1.0
            p1 = (m1 & 0x3F803F80u) | (~m1 & p1);
            uint2 pk2; pk2.x = p0; pk2.y = p1;
            *(uint2*)((char*)Ps + qr * 128 +
                      (((2 * mt + (quad >> 1)) ^ sw7) * 16) + (quad & 1) * 8) = pk2;
        }

        // 5) O += P·V ; lsum += P·1
        #pragma unroll
        for (int kst = 0; kst < 2; ++kst) {
            bf16x8 vfr[4];
            #pragma unroll
            for (int dt = 0; dt < 4; ++dt) {
                const int R = dt * 16 + l15;
                vfr[dt] = *(const bf16x8*)&Vs[cur][R * 64 + (((kst * 4 + quad) ^ sw7) * 8)];
            }
            bf16x8 pfr = *(const bf16x8*)((const char*)Ps + qr * 128 +
                                          (((kst * 4 + quad) ^ sw7) * 16));
            __builtin_amdgcn_s_setprio(1);
            #pragma unroll
            for (int dt = 0; dt < 4; ++dt)
                accO[dt] = __builtin_amdgcn_mfma_f32_16x16x32_bf16(pfr, vfr[dt], accO[dt], 0, 0, 0);
            lsA = __builtin_amdgcn_mfma_f32_16x16x32_bf16(pfr, ones, lsA, 0, 0, 0);
            __builtin_amdgcn_s_setprio(0);
        }
    }

    // normalize + store
    float* __restrict__ ob = out + ((size_t)b * S_ + q0) * D_ + (size_t)h * HD_;
    #pragma unroll
    for (int r = 0; r < 4; ++r) {
        const float inv = 1.0f / lsA[r];
        const int row = w * 16 + quad * 4 + r;
        #pragma unroll
        for (int dt = 0; dt < 4; ++dt)
            ob[(size_t)row * D_ + dt * 16 + l15] = accO[dt][r] * inv;
    }
}

extern "C" void kernel_launch(void* const* d_in, const int* in_sizes, int n_in,
                              void* d_out, int out_size, void* d_ws, size_t ws_size,
                              hipStream_t stream) {
    (void)in_sizes; (void)n_in; (void)out_size; (void)ws_size;
    const float* x    = (const float*)d_in[0];
    const int*   mask = (const int*)d_in[1];
    const float* Wq   = (const float*)d_in[2];
    const float* bq   = (const float*)d_in[3];
    const float* Wk   = (const float*)d_in[4];
    const float* bk   = (const float*)d_in[5];
    const float* Wv   = (const float*)d_in[6];
    const float* bv   = (const float*)d_in[7];
    float* out = (float*)d_out;

    const size_t M1 = (size_t)1024 * 1024;
    unsigned short* xb  = (unsigned short*)d_ws;      // 4M bf16
    unsigned short* wtb = xb + 4 * M1;                // 3M bf16
    unsigned short* qb  = wtb + 3 * M1;               // 4M bf16
    unsigned short* kb  = qb + 4 * M1;                // 4M bf16
    unsigned short* vtb = kb + 4 * M1;                // 4M bf16 (transposed V)
    unsigned char*  mk  = (unsigned char*)(vtb + 4 * M1);  // 8M u8 (0xFF/0x00)

    prep<<<4864, 256, 0, stream>>>(x, xb, mask, mk, Wq, Wk, Wv, wtb);
    qkv_gemm<<<dim3(24, 32), 512, 0, stream>>>(xb, wtb, bq, bk, bv, qb, kb, vtb);
    attn_mfma<<<dim3(16, 16, 2), 512, 0, stream>>>(qb, kb, vtb, mk, out);
}